// Round 4
// baseline (1198.685 us; speedup 1.0000x reference)
//
#include <hip/hip_runtime.h>
#include <hip/hip_bf16.h>
#include <cstddef>
#include <cstdint>

typedef unsigned short u16;

#define Mtok  16384
#define Ncode 8192
#define Kdim  256
#define NSPLIT 8
#define NPER  (Ncode / NSPLIT)    // 1024 codes per split
#define NT    (NPER / 128)        // 8 column tiles of 128 per block
#define TH_MARGIN 0.02f

typedef __bf16 bf16x8 __attribute__((ext_vector_type(8)));
typedef float  f32x4  __attribute__((ext_vector_type(4)));

#define LDSP(p) ((__attribute__((address_space(3))) void*)(p))
#define GPTR(p) ((const __attribute__((address_space(1))) void*)(p))

__device__ __forceinline__ u16 f2bf(float x) {
    __hip_bfloat16 h = __float2bfloat16(x);
    return *reinterpret_cast<u16*>(&h);
}
__device__ __forceinline__ float bf2f(u16 u) {
    __hip_bfloat16 h = *reinterpret_cast<__hip_bfloat16*>(&u);
    return __bfloat162float(h);
}

// ---------------------------------------------------------------------------
// Kernel 1: transpose z -> z_out (fp32), plus bf16 split of s = -2*z:
// sh = bf16(s), sl = bf16(s - sh), stored [Mtok][256] row-major.
__global__ __launch_bounds__(256) void k_prep(const float* __restrict__ z,
        float* __restrict__ z_out, u16* __restrict__ sh, u16* __restrict__ sl) {
    __shared__ float tile[32][33];
    const int b  = blockIdx.z;
    const int c0 = blockIdx.y * 32;
    const int p0 = blockIdx.x * 32;
    const int tx = threadIdx.x;   // 0..31
    const int ty = threadIdx.y;   // 0..7
    const float* src = z + ((size_t)b * Kdim + c0) * 1024 + p0;
#pragma unroll
    for (int i = 0; i < 32; i += 8)
        tile[ty + i][tx] = src[(size_t)(ty + i) * 1024 + tx];
    __syncthreads();
#pragma unroll
    for (int i = 0; i < 32; i += 8) {
        const float v = tile[tx][ty + i];
        const size_t m = (size_t)b * 1024 + p0 + ty + i;
        const int    c = c0 + tx;
        z_out[m * Kdim + c] = v;
        const float s  = -2.0f * v;
        const u16   hb = f2bf(s);
        const u16   lb = f2bf(s - bf2f(hb));
        sh[m * Kdim + c] = hb;
        sl[m * Kdim + c] = lb;
    }
}

// ---------------------------------------------------------------------------
// Kernel 2: per-code ||w||^2 plus bf16 split wh/wl. One wave per code row.
__global__ __launch_bounds__(64) void k_wsplit(const float* __restrict__ w,
        float* __restrict__ wnorm, u16* __restrict__ wh, u16* __restrict__ wl) {
    const int row  = blockIdx.x;
    const int lane = threadIdx.x;
    const float4 v = ((const float4*)(w + (size_t)row * Kdim))[lane];
    float s = v.x * v.x + v.y * v.y + v.z * v.z + v.w * v.w;
#pragma unroll
    for (int off = 32; off > 0; off >>= 1)
        s += __shfl_down(s, off, 64);
    if (lane == 0) wnorm[row] = s;
    const float e[4] = {v.x, v.y, v.z, v.w};
    ushort4 ph, pl;
    u16* hp = (u16*)&ph; u16* lp = (u16*)&pl;
#pragma unroll
    for (int i = 0; i < 4; ++i) {
        const u16 hb = f2bf(e[i]);
        hp[i] = hb;
        lp[i] = f2bf(e[i] - bf2f(hb));
    }
    *(ushort4*)(wh + (size_t)row * Kdim + lane * 4) = ph;
    *(ushort4*)(wl + (size_t)row * Kdim + lane * 4) = pl;
}

// ---------------------------------------------------------------------------
// Kernel 3: bf16 MFMA distance GEMM + per-row running top-2 (val1, idx1, val2).
// d(m,n) = wnorm[n] + (sh*wh + sh*wl + sl*wh), single merged k-loop:
// 4 matrices staged per 32-k chunk (32 KB LDS), 48 MFMAs per barrier-pair.
__global__ __launch_bounds__(256, 3) void k_mfma(
        const u16* __restrict__ sh, const u16* __restrict__ sl,
        const u16* __restrict__ wh, const u16* __restrict__ wl,
        const float* __restrict__ wnorm,
        float* __restrict__ pv1, int* __restrict__ pi1, float* __restrict__ pv2) {
    __shared__ __align__(16) u16 Ah[128 * 32];
    __shared__ __align__(16) u16 Al[128 * 32];
    __shared__ __align__(16) u16 Bh[128 * 32];
    __shared__ __align__(16) u16 Bl[128 * 32];
    const int tid  = threadIdx.x;
    const int w    = tid >> 6;          // wave 0..3
    const int lane = tid & 63;
    const int l15  = lane & 15;
    const int q    = lane >> 4;         // 0..3
    const int y    = blockIdx.x & 7;    // n-split (XCD pin)
    const int x    = blockIdx.x >> 3;   // m-tile
    const int m0   = x * 128;
    const int n0   = y * NPER;
    const int srow = lane >> 2;         // staging: 16 rows x 4 16B-chunks
    const int sq   = lane & 3;

    float v1[8], v2[8]; int i1[8];      // slot s=i*4+r -> row m0+w*32+i*16+q*4+r
#pragma unroll
    for (int s = 0; s < 8; ++s) { v1[s] = 3.0e38f; v2[s] = 3.0e38f; i1[s] = 0x7fffffff; }

    for (int nt = 0; nt < NT; ++nt) {
        const int nb = n0 + nt * 128;
        f32x4 acc[2][8];
#pragma unroll
        for (int j = 0; j < 8; ++j) {
            const float wv = wnorm[nb + j * 16 + l15];
#pragma unroll
            for (int i = 0; i < 2; ++i) {
                acc[i][j][0] = wv; acc[i][j][1] = wv;
                acc[i][j][2] = wv; acc[i][j][3] = wv;
            }
        }
#pragma unroll 1
        for (int k0 = 0; k0 < Kdim; k0 += 32) {
            __syncthreads();
#pragma unroll
            for (int t = 0; t < 2; ++t) {
                const int rb = w * 32 + t * 16;   // wave-uniform LDS row base
                const size_t ga = (size_t)(m0 + rb + srow) * Kdim + k0 + sq * 8;
                const size_t gb = (size_t)(nb + rb + srow) * Kdim + k0 + sq * 8;
                __builtin_amdgcn_global_load_lds(GPTR(sh + ga), LDSP(Ah + rb * 32), 16, 0, 0);
                __builtin_amdgcn_global_load_lds(GPTR(sl + ga), LDSP(Al + rb * 32), 16, 0, 0);
                __builtin_amdgcn_global_load_lds(GPTR(wh + gb), LDSP(Bh + rb * 32), 16, 0, 0);
                __builtin_amdgcn_global_load_lds(GPTR(wl + gb), LDSP(Bl + rb * 32), 16, 0, 0);
            }
            __syncthreads();
            bf16x8 ah[2], al[2];
#pragma unroll
            for (int i = 0; i < 2; ++i) {
                ah[i] = *(const bf16x8*)&Ah[(w * 32 + i * 16 + l15) * 32 + q * 8];
                al[i] = *(const bf16x8*)&Al[(w * 32 + i * 16 + l15) * 32 + q * 8];
            }
#pragma unroll
            for (int j = 0; j < 8; ++j) {
                const bf16x8 bh = *(const bf16x8*)&Bh[(j * 16 + l15) * 32 + q * 8];
                const bf16x8 bl = *(const bf16x8*)&Bl[(j * 16 + l15) * 32 + q * 8];
                acc[0][j] = __builtin_amdgcn_mfma_f32_16x16x32_bf16(ah[0], bh, acc[0][j], 0, 0, 0);
                acc[1][j] = __builtin_amdgcn_mfma_f32_16x16x32_bf16(ah[1], bh, acc[1][j], 0, 0, 0);
                acc[0][j] = __builtin_amdgcn_mfma_f32_16x16x32_bf16(ah[0], bl, acc[0][j], 0, 0, 0);
                acc[1][j] = __builtin_amdgcn_mfma_f32_16x16x32_bf16(ah[1], bl, acc[1][j], 0, 0, 0);
                acc[0][j] = __builtin_amdgcn_mfma_f32_16x16x32_bf16(al[0], bh, acc[0][j], 0, 0, 0);
                acc[1][j] = __builtin_amdgcn_mfma_f32_16x16x32_bf16(al[1], bh, acc[1][j], 0, 0, 0);
            }
        }
        // top-2 update (idx ascending per lane scan -> strict < = first-min)
#pragma unroll
        for (int i = 0; i < 2; ++i)
#pragma unroll
            for (int r = 0; r < 4; ++r) {
                const int s = i * 4 + r;
#pragma unroll
                for (int j = 0; j < 8; ++j) {
                    const float d   = acc[i][j][r];
                    const int   idx = nb + j * 16 + l15;
                    const bool  bt  = d < v1[s];
                    const float lose = bt ? v1[s] : d;
                    v2[s] = fminf(v2[s], lose);
                    v1[s] = bt ? d : v1[s];
                    i1[s] = bt ? idx : i1[s];
                }
            }
    }
    // butterfly merge across the 16 lanes sharing each row (lex on idx)
#pragma unroll
    for (int msk = 1; msk < 16; msk <<= 1) {
#pragma unroll
        for (int s = 0; s < 8; ++s) {
            const float ov1 = __shfl_xor(v1[s], msk, 64);
            const int   oi1 = __shfl_xor(i1[s], msk, 64);
            const float ov2 = __shfl_xor(v2[s], msk, 64);
            const bool  keep = (v1[s] < ov1) || (v1[s] == ov1 && i1[s] < oi1);
            const float lose = keep ? ov1 : v1[s];
            v1[s] = keep ? v1[s] : ov1;
            i1[s] = keep ? i1[s] : oi1;
            v2[s] = fminf(fminf(v2[s], ov2), lose);
        }
    }
    if (l15 == 0) {
#pragma unroll
        for (int i = 0; i < 2; ++i)
#pragma unroll
            for (int r = 0; r < 4; ++r) {
                const int s = i * 4 + r;
                const int m = m0 + w * 32 + i * 16 + q * 4 + r;
                pv1[(size_t)y * Mtok + m] = v1[s];
                pi1[(size_t)y * Mtok + m] = i1[s];
                pv2[(size_t)y * Mtok + m] = v2[s];
            }
    }
}

// ---------------------------------------------------------------------------
// Kernel 4: merge 8 split partials -> provisional idx + ambiguity flag.
__global__ __launch_bounds__(256) void k_merge(
        const float* __restrict__ pv1, const int* __restrict__ pi1,
        const float* __restrict__ pv2, int* __restrict__ fidx,
        int* __restrict__ flag) {
    const int t = blockIdx.x * 256 + threadIdx.x;
    float b1 = 3.0e38f, b2 = 3.0e38f; int bi = 0x7fffffff;
#pragma unroll
    for (int s = 0; s < NSPLIT; ++s) {
        const float v1 = pv1[(size_t)s * Mtok + t];
        const int   i1 = pi1[(size_t)s * Mtok + t];
        const float v2 = pv2[(size_t)s * Mtok + t];
        const bool  wn = (v1 < b1) || (v1 == b1 && i1 < bi);
        const float lose = wn ? b1 : v1;
        b2 = fminf(fminf(b2, v2), lose);
        b1 = wn ? v1 : b1;
        bi = wn ? i1 : bi;
    }
    fidx[t] = bi;
    flag[t] = (b2 - b1 < TH_MARGIN) ? 1 : 0;
}

// ---------------------------------------------------------------------------
// Kernel 5: exact fp32 rescore for flagged tokens, COALESCED:
// each wave reads one full contiguous code row (64 lanes x float4 = 1 KB)
// per iteration; z kept in registers; butterfly xor-reduce (lane-uniform,
// so lexicographic tie-break is exact).
__global__ __launch_bounds__(256) void k_rescue(
        const float* __restrict__ z_out, const float* __restrict__ w,
        const float* __restrict__ wnorm, const int* __restrict__ flag,
        int* __restrict__ fidx) {
    const int t = blockIdx.x;
    if (!flag[t]) return;
    __shared__ float rv[4];
    __shared__ int   ri[4];
    const int tid  = threadIdx.x;
    const int wv   = tid >> 6;     // wave 0..3
    const int lane = tid & 63;
    const float4 zv = *(const float4*)(z_out + (size_t)t * Kdim + lane * 4);
    float bd = 3.0e38f; int bn = 0x7fffffff;
#pragma unroll 4
    for (int n = wv; n < Ncode; n += 4) {       // ascending per wave
        const float4 wr = *(const float4*)(w + (size_t)n * Kdim + lane * 4);
        float s = wr.x * zv.x + wr.y * zv.y + wr.z * zv.z + wr.w * zv.w;
#pragma unroll
        for (int msk = 1; msk < 64; msk <<= 1)
            s += __shfl_xor(s, msk, 64);        // uniform across lanes
        const float d = wnorm[n] - 2.0f * s;
        if (d < bd) { bd = d; bn = n; }
    }
    if (lane == 0) { rv[wv] = bd; ri[wv] = bn; }
    __syncthreads();
    if (tid == 0) {
        float b = rv[0]; int bi = ri[0];
#pragma unroll
        for (int i = 1; i < 4; ++i) {
            if (rv[i] < b || (rv[i] == b && ri[i] < bi)) { b = rv[i]; bi = ri[i]; }
        }
        fidx[t] = bi;
    }
}

// ---------------------------------------------------------------------------
// Kernel 6: gather z_q = weight[fidx], write float indices. One wave/token.
__global__ __launch_bounds__(256) void k_gather(
        const float* __restrict__ w, const int* __restrict__ fidx,
        float* __restrict__ zq, float* __restrict__ idx_out) {
    const int token = blockIdx.x * 4 + (threadIdx.x >> 6);
    const int lane  = threadIdx.x & 63;
    const int bi    = fidx[token];
    const float4 u = *(const float4*)(w + (size_t)bi * Kdim + lane * 4);
    *(float4*)(zq + (size_t)token * Kdim + lane * 4) = u;
    if (lane == 0) idx_out[token] = (float)bi;
}

// ---------------------------------------------------------------------------
extern "C" void kernel_launch(void* const* d_in, const int* in_sizes, int n_in,
                              void* d_out, int out_size, void* d_ws, size_t ws_size,
                              hipStream_t stream) {
    const float* z = (const float*)d_in[0];
    const float* w = (const float*)d_in[1];

    float* z_out  = (float*)d_out;                          // [16384, 256]
    float* zq     = z_out + (size_t)Mtok * Kdim;            // [16384, 256]
    float* idxout = zq + (size_t)Mtok * Kdim;               // [16384]

    char* ws = (char*)d_ws;
    u16*   sh    = (u16*)ws;                       ws += (size_t)Mtok * Kdim * 2;
    u16*   sl    = (u16*)ws;                       ws += (size_t)Mtok * Kdim * 2;
    u16*   wh    = (u16*)ws;                       ws += (size_t)Ncode * Kdim * 2;
    u16*   wl    = (u16*)ws;                       ws += (size_t)Ncode * Kdim * 2;
    float* wnorm = (float*)ws;                     ws += (size_t)Ncode * 4;
    float* pv1   = (float*)ws;                     ws += (size_t)NSPLIT * Mtok * 4;
    int*   pi1   = (int*)ws;                       ws += (size_t)NSPLIT * Mtok * 4;
    float* pv2   = (float*)ws;                     ws += (size_t)NSPLIT * Mtok * 4;
    int*   fidx  = (int*)ws;                       ws += (size_t)Mtok * 4;
    int*   flag  = (int*)ws;                       ws += (size_t)Mtok * 4;

    k_prep<<<dim3(1024 / 32, Kdim / 32, 16), dim3(32, 8), 0, stream>>>(z, z_out, sh, sl);
    k_wsplit<<<dim3(Ncode), dim3(64), 0, stream>>>(w, wnorm, wh, wl);
    k_mfma<<<dim3(128 * NSPLIT), dim3(256), 0, stream>>>(sh, sl, wh, wl, wnorm,
                                                         pv1, pi1, pv2);
    k_merge<<<dim3(Mtok / 256), dim3(256), 0, stream>>>(pv1, pi1, pv2, fidx, flag);
    k_rescue<<<dim3(Mtok), dim3(256), 0, stream>>>(z_out, w, wnorm, flag, fidx);
    k_gather<<<dim3(Mtok / 4), dim3(256), 0, stream>>>(w, fidx, zq, idxout);
}

// Round 5
// 411.237 us; speedup vs baseline: 2.9148x; 2.9148x over previous
//
#include <hip/hip_runtime.h>
#include <hip/hip_bf16.h>
#include <cstddef>
#include <cstdint>

typedef unsigned short u16;

#define Mtok  16384
#define Ncode 8192
#define Kdim  256
#define NSPLIT 8
#define NPER  (Ncode / NSPLIT)    // 1024 codes per split
#define NT    (NPER / 128)        // 8 column tiles of 128 per block
#define TH_MARGIN 0.02f
#define RCHUNK 256                // rescue: codes per chunk
#define RNCH  (Ncode / RCHUNK)    // 32 chunks

typedef __bf16 bf16x8 __attribute__((ext_vector_type(8)));
typedef float  f32x4  __attribute__((ext_vector_type(4)));

#define LDSP(p) ((__attribute__((address_space(3))) void*)(p))
#define GPTR(p) ((const __attribute__((address_space(1))) void*)(p))

__device__ __forceinline__ u16 f2bf(float x) {
    __hip_bfloat16 h = __float2bfloat16(x);
    return *reinterpret_cast<u16*>(&h);
}
__device__ __forceinline__ float bf2f(u16 u) {
    __hip_bfloat16 h = *reinterpret_cast<__hip_bfloat16*>(&u);
    return __bfloat162float(h);
}

// ---------------------------------------------------------------------------
// Kernel 1: transpose z -> z_out (fp32), plus bf16 split of s = -2*z.
// Also zeroes the rescue counter (stream-ordered before k_merge).
__global__ __launch_bounds__(256) void k_prep(const float* __restrict__ z,
        float* __restrict__ z_out, u16* __restrict__ sh, u16* __restrict__ sl,
        int* __restrict__ count) {
    __shared__ float tile[32][33];
    const int b  = blockIdx.z;
    const int c0 = blockIdx.y * 32;
    const int p0 = blockIdx.x * 32;
    const int tx = threadIdx.x;   // 0..31
    const int ty = threadIdx.y;   // 0..7
    if (b == 0 && c0 == 0 && p0 == 0 && tx == 0 && ty == 0) count[0] = 0;
    const float* src = z + ((size_t)b * Kdim + c0) * 1024 + p0;
#pragma unroll
    for (int i = 0; i < 32; i += 8)
        tile[ty + i][tx] = src[(size_t)(ty + i) * 1024 + tx];
    __syncthreads();
#pragma unroll
    for (int i = 0; i < 32; i += 8) {
        const float v = tile[tx][ty + i];
        const size_t m = (size_t)b * 1024 + p0 + ty + i;
        const int    c = c0 + tx;
        z_out[m * Kdim + c] = v;
        const float s  = -2.0f * v;
        const u16   hb = f2bf(s);
        const u16   lb = f2bf(s - bf2f(hb));
        sh[m * Kdim + c] = hb;
        sl[m * Kdim + c] = lb;
    }
}

// ---------------------------------------------------------------------------
// Kernel 2: per-code ||w||^2 plus bf16 split wh/wl. One wave per code row.
__global__ __launch_bounds__(64) void k_wsplit(const float* __restrict__ w,
        float* __restrict__ wnorm, u16* __restrict__ wh, u16* __restrict__ wl) {
    const int row  = blockIdx.x;
    const int lane = threadIdx.x;
    const float4 v = ((const float4*)(w + (size_t)row * Kdim))[lane];
    float s = v.x * v.x + v.y * v.y + v.z * v.z + v.w * v.w;
#pragma unroll
    for (int off = 32; off > 0; off >>= 1)
        s += __shfl_down(s, off, 64);
    if (lane == 0) wnorm[row] = s;
    const float e[4] = {v.x, v.y, v.z, v.w};
    ushort4 ph, pl;
    u16* hp = (u16*)&ph; u16* lp = (u16*)&pl;
#pragma unroll
    for (int i = 0; i < 4; ++i) {
        const u16 hb = f2bf(e[i]);
        hp[i] = hb;
        lp[i] = f2bf(e[i] - bf2f(hb));
    }
    *(ushort4*)(wh + (size_t)row * Kdim + lane * 4) = ph;
    *(ushort4*)(wl + (size_t)row * Kdim + lane * 4) = pl;
}

// ---------------------------------------------------------------------------
// Kernel 3 (round-3 version, the merged variant regressed): bf16 MFMA distance
// GEMM + per-row top-2. d(m,n) = wnorm[n] + (sh*wh + sh*wl + sl*wh), 3 passes.
__global__ __launch_bounds__(256) void k_mfma(
        const u16* __restrict__ sh, const u16* __restrict__ sl,
        const u16* __restrict__ wh, const u16* __restrict__ wl,
        const float* __restrict__ wnorm,
        float* __restrict__ pv1, int* __restrict__ pi1, float* __restrict__ pv2) {
    __shared__ __align__(16) u16 As[128 * 32];
    __shared__ __align__(16) u16 Bs[128 * 32];
    const int tid  = threadIdx.x;
    const int w    = tid >> 6;          // wave 0..3
    const int lane = tid & 63;
    const int l15  = lane & 15;
    const int q    = lane >> 4;         // 0..3
    const int y    = blockIdx.x & 7;    // n-split (XCD pin)
    const int x    = blockIdx.x >> 3;   // m-tile
    const int m0   = x * 128;
    const int n0   = y * NPER;
    const int srow = lane >> 2;         // staging: 16 rows x 4 16B-chunks
    const int sq   = lane & 3;

    const u16* Alist[3] = {sh, sh, sl};
    const u16* Blist[3] = {wh, wl, wh};

    float v1[8], v2[8]; int i1[8];      // slot s=i*4+r -> row m0+w*32+i*16+q*4+r
#pragma unroll
    for (int s = 0; s < 8; ++s) { v1[s] = 3.0e38f; v2[s] = 3.0e38f; i1[s] = 0x7fffffff; }

    for (int nt = 0; nt < NT; ++nt) {
        const int nb = n0 + nt * 128;
        f32x4 acc[2][8];
#pragma unroll
        for (int j = 0; j < 8; ++j) {
            const float wv = wnorm[nb + j * 16 + l15];
#pragma unroll
            for (int i = 0; i < 2; ++i) {
                acc[i][j][0] = wv; acc[i][j][1] = wv;
                acc[i][j][2] = wv; acc[i][j][3] = wv;
            }
        }
#pragma unroll 1
        for (int pr = 0; pr < 3; ++pr) {
            const u16* Ag = Alist[pr];
            const u16* Bg = Blist[pr];
#pragma unroll 1
            for (int k0 = 0; k0 < Kdim; k0 += 32) {
                __syncthreads();
#pragma unroll
                for (int t = 0; t < 2; ++t) {
                    const int r = w * 32 + t * 16 + srow;
                    __builtin_amdgcn_global_load_lds(
                        GPTR(Ag + (size_t)(m0 + r) * Kdim + k0 + sq * 8),
                        LDSP(As + (w * 32 + t * 16) * 32), 16, 0, 0);
                    __builtin_amdgcn_global_load_lds(
                        GPTR(Bg + (size_t)(nb + r) * Kdim + k0 + sq * 8),
                        LDSP(Bs + (w * 32 + t * 16) * 32), 16, 0, 0);
                }
                __syncthreads();
                bf16x8 a[2], bfr[8];
#pragma unroll
                for (int i = 0; i < 2; ++i)
                    a[i] = *(const bf16x8*)&As[(w * 32 + i * 16 + l15) * 32 + q * 8];
#pragma unroll
                for (int j = 0; j < 8; ++j)
                    bfr[j] = *(const bf16x8*)&Bs[(j * 16 + l15) * 32 + q * 8];
#pragma unroll
                for (int i = 0; i < 2; ++i)
#pragma unroll
                    for (int j = 0; j < 8; ++j)
                        acc[i][j] = __builtin_amdgcn_mfma_f32_16x16x32_bf16(
                            a[i], bfr[j], acc[i][j], 0, 0, 0);
            }
        }
        // top-2 update (idx ascending per lane scan -> strict < = first-min)
#pragma unroll
        for (int i = 0; i < 2; ++i)
#pragma unroll
            for (int r = 0; r < 4; ++r) {
                const int s = i * 4 + r;
#pragma unroll
                for (int j = 0; j < 8; ++j) {
                    const float d   = acc[i][j][r];
                    const int   idx = nb + j * 16 + l15;
                    const bool  bt  = d < v1[s];
                    const float lose = bt ? v1[s] : d;
                    v2[s] = fminf(v2[s], lose);
                    v1[s] = bt ? d : v1[s];
                    i1[s] = bt ? idx : i1[s];
                }
            }
    }
    // butterfly merge across the 16 lanes sharing each row (lex on idx)
#pragma unroll
    for (int msk = 1; msk < 16; msk <<= 1) {
#pragma unroll
        for (int s = 0; s < 8; ++s) {
            const float ov1 = __shfl_xor(v1[s], msk, 64);
            const int   oi1 = __shfl_xor(i1[s], msk, 64);
            const float ov2 = __shfl_xor(v2[s], msk, 64);
            const bool  keep = (v1[s] < ov1) || (v1[s] == ov1 && i1[s] < oi1);
            const float lose = keep ? ov1 : v1[s];
            v1[s] = keep ? v1[s] : ov1;
            i1[s] = keep ? i1[s] : oi1;
            v2[s] = fminf(fminf(v2[s], ov2), lose);
        }
    }
    if (l15 == 0) {
#pragma unroll
        for (int i = 0; i < 2; ++i)
#pragma unroll
            for (int r = 0; r < 4; ++r) {
                const int s = i * 4 + r;
                const int m = m0 + w * 32 + i * 16 + q * 4 + r;
                pv1[(size_t)y * Mtok + m] = v1[s];
                pi1[(size_t)y * Mtok + m] = i1[s];
                pv2[(size_t)y * Mtok + m] = v2[s];
            }
    }
}

// ---------------------------------------------------------------------------
// Kernel 4: merge 8 split partials -> provisional idx + flag + compacted list.
__global__ __launch_bounds__(256) void k_merge(
        const float* __restrict__ pv1, const int* __restrict__ pi1,
        const float* __restrict__ pv2, int* __restrict__ fidx,
        int* __restrict__ flag, int* __restrict__ list, int* __restrict__ count) {
    const int t = blockIdx.x * 256 + threadIdx.x;
    float b1 = 3.0e38f, b2 = 3.0e38f; int bi = 0x7fffffff;
#pragma unroll
    for (int s = 0; s < NSPLIT; ++s) {
        const float v1 = pv1[(size_t)s * Mtok + t];
        const int   i1 = pi1[(size_t)s * Mtok + t];
        const float v2 = pv2[(size_t)s * Mtok + t];
        const bool  wn = (v1 < b1) || (v1 == b1 && i1 < bi);
        const float lose = wn ? b1 : v1;
        b2 = fminf(fminf(b2, v2), lose);
        b1 = wn ? v1 : b1;
        bi = wn ? i1 : bi;
    }
    fidx[t] = bi;
    const int f = (b2 - b1 < TH_MARGIN) ? 1 : 0;
    flag[t] = f;
    if (f) { const int p = atomicAdd(count, 1); list[p] = t; }
}

// ---------------------------------------------------------------------------
// Kernel 5: exact fp32 rescore, parallelized over code chunks.
// grid (RNCH, 64): block = (chunk bx, one listed token per y-iteration).
// Each wave handles codes n = bx*256 + 4*i + wv (ascending), whole-row
// coalesced 1 KB reads, 64-lane butterfly dot-reduce. Cross-wave lex merge
// -> one (val,idx) partial per (token, chunk).
__global__ __launch_bounds__(256) void k_rescue(
        const float* __restrict__ z_out, const float* __restrict__ w,
        const float* __restrict__ wnorm, const int* __restrict__ list,
        const int* __restrict__ count,
        float* __restrict__ pcv, int* __restrict__ pci) {
    const int bx   = blockIdx.x;       // chunk
    const int tid  = threadIdx.x;
    const int wv   = tid >> 6;
    const int lane = tid & 63;
    __shared__ float rv[4];
    __shared__ int   ri[4];
    const int cnt = count[0];
    for (int it = blockIdx.y; it < cnt; it += gridDim.y) {
        const int t = list[it];
        const float4 zv = *(const float4*)(z_out + (size_t)t * Kdim + lane * 4);
        float bd = 3.0e38f; int bn = 0x7fffffff;
#pragma unroll 4
        for (int i = 0; i < RCHUNK / 4; ++i) {
            const int n = bx * RCHUNK + i * 4 + wv;
            const float4 wr = *(const float4*)(w + (size_t)n * Kdim + lane * 4);
            float s = fmaf(wr.x, zv.x, fmaf(wr.y, zv.y,
                      fmaf(wr.z, zv.z, wr.w * zv.w)));
#pragma unroll
            for (int msk = 1; msk < 64; msk <<= 1)
                s += __shfl_xor(s, msk, 64);
            const float d = wnorm[n] - 2.0f * s;
            if (d < bd) { bd = d; bn = n; }
        }
        if (lane == 0) { rv[wv] = bd; ri[wv] = bn; }
        __syncthreads();
        if (tid == 0) {
            float b = rv[0]; int bi = ri[0];
#pragma unroll
            for (int k = 1; k < 4; ++k)
                if (rv[k] < b || (rv[k] == b && ri[k] < bi)) { b = rv[k]; bi = ri[k]; }
            pcv[(size_t)t * RNCH + bx] = b;
            pci[(size_t)t * RNCH + bx] = bi;
        }
        __syncthreads();
    }
}

// ---------------------------------------------------------------------------
// Kernel 6: gather z_q = weight[idx], write float indices. One wave/token.
// For flagged tokens, merge the RNCH rescue partials in-wave first.
__global__ __launch_bounds__(256) void k_gather(
        const float* __restrict__ w, const int* __restrict__ fidx,
        const int* __restrict__ flag,
        const float* __restrict__ pcv, const int* __restrict__ pci,
        float* __restrict__ zq, float* __restrict__ idx_out) {
    const int token = blockIdx.x * 4 + (threadIdx.x >> 6);
    const int lane  = threadIdx.x & 63;
    int bi = fidx[token];
    if (flag[token]) {
        float v = 3.0e38f; int ii = 0x7fffffff;
        if (lane < RNCH) {
            v  = pcv[(size_t)token * RNCH + lane];
            ii = pci[(size_t)token * RNCH + lane];
        }
#pragma unroll
        for (int msk = 1; msk < 64; msk <<= 1) {
            const float ov = __shfl_xor(v, msk, 64);
            const int   oi = __shfl_xor(ii, msk, 64);
            if (ov < v || (ov == v && oi < ii)) { v = ov; ii = oi; }
        }
        bi = ii;   // uniform across lanes after full butterfly
    }
    const float4 u = *(const float4*)(w + (size_t)bi * Kdim + lane * 4);
    *(float4*)(zq + (size_t)token * Kdim + lane * 4) = u;
    if (lane == 0) idx_out[token] = (float)bi;
}

// ---------------------------------------------------------------------------
extern "C" void kernel_launch(void* const* d_in, const int* in_sizes, int n_in,
                              void* d_out, int out_size, void* d_ws, size_t ws_size,
                              hipStream_t stream) {
    const float* z = (const float*)d_in[0];
    const float* w = (const float*)d_in[1];

    float* z_out  = (float*)d_out;                          // [16384, 256]
    float* zq     = z_out + (size_t)Mtok * Kdim;            // [16384, 256]
    float* idxout = zq + (size_t)Mtok * Kdim;               // [16384]

    char* ws = (char*)d_ws;
    u16*   sh    = (u16*)ws;                       ws += (size_t)Mtok * Kdim * 2;
    u16*   sl    = (u16*)ws;                       ws += (size_t)Mtok * Kdim * 2;
    u16*   wh    = (u16*)ws;                       ws += (size_t)Ncode * Kdim * 2;
    u16*   wl    = (u16*)ws;                       ws += (size_t)Ncode * Kdim * 2;
    float* wnorm = (float*)ws;                     ws += (size_t)Ncode * 4;
    float* pv1   = (float*)ws;                     ws += (size_t)NSPLIT * Mtok * 4;
    int*   pi1   = (int*)ws;                       ws += (size_t)NSPLIT * Mtok * 4;
    float* pv2   = (float*)ws;                     ws += (size_t)NSPLIT * Mtok * 4;
    int*   fidx  = (int*)ws;                       ws += (size_t)Mtok * 4;
    int*   flag  = (int*)ws;                       ws += (size_t)Mtok * 4;
    int*   list  = (int*)ws;                       ws += (size_t)Mtok * 4;
    int*   count = (int*)ws;                       ws += 256;
    float* pcv   = (float*)ws;                     ws += (size_t)Mtok * RNCH * 4;
    int*   pci   = (int*)ws;                       ws += (size_t)Mtok * RNCH * 4;

    k_prep<<<dim3(1024 / 32, Kdim / 32, 16), dim3(32, 8), 0, stream>>>(z, z_out, sh, sl, count);
    k_wsplit<<<dim3(Ncode), dim3(64), 0, stream>>>(w, wnorm, wh, wl);
    k_mfma<<<dim3(128 * NSPLIT), dim3(256), 0, stream>>>(sh, sl, wh, wl, wnorm,
                                                         pv1, pi1, pv2);
    k_merge<<<dim3(Mtok / 256), dim3(256), 0, stream>>>(pv1, pi1, pv2, fidx, flag,
                                                        list, count);
    k_rescue<<<dim3(RNCH, 64), dim3(256), 0, stream>>>(z_out, w, wnorm, list, count,
                                                       pcv, pci);
    k_gather<<<dim3(Mtok / 4), dim3(256), 0, stream>>>(w, fidx, flag, pcv, pci,
                                                       zq, idxout);
}